// Round 2
// baseline (393.207 us; speedup 1.0000x reference)
//
#include <hip/hip_runtime.h>

// SpecEMA: y[b,c,t,f] = x[b,c,t,f] / sqrt(s[b,t,f]),
//   s_t = ALPHA*s_{t-1} + (1-ALPHA)*(x[b,0,t,f]^2 + x[b,1,t,f]^2), s_{-1}=state[f]
// Outputs: y [64,2,4000,96] then final_state [64,1,96], flat-concatenated in d_out.
//
// Three-phase linear-scan decomposition over K chunks of length L (T = K*L):
//   phase1: B_k = chunk-local EMA with s_in = 0   (one thread per chain*chunk)
//   phase2: tiny serial scan over k (1536 threads, L2-resident, ~3 us):
//           in-place converts bws[k][chain] from B_k to s_in(k)
//   phase3: s = load s_in(k); scan chunk, normalize, NT-store y.
//
// K=250/L=16 (was 100/40): 1494/1500 blocks (~5.9 blocks/CU, ~23 waves/CU).
// The dedicated phase2 removes phase3's O(K) per-thread prefix loop, which is
// what previously made large K expensive — occupancy is now decoupled from
// the recombination cost.

namespace {
constexpr int Bdim = 64, Cdim = 2, Tdim = 4000, Fdim = 96;
constexpr int K = 250, L = 16;             // T = K * L
constexpr int FG = Fdim / 4;               // 24 float4 groups per (b, c, t)
constexpr int CHAINS = Bdim * FG;          // 1536 float4-chains
constexpr float kAlpha = 0.99f;
constexpr float kOneMinusAlpha = 0.01f;    // float(1.0 - 0.99)
constexpr float kAlphaL = 0.85145784f;     // 0.99^16

typedef float v4f __attribute__((ext_vector_type(4)));

__device__ __forceinline__ v4f ld4(const float* p) {
  return *reinterpret_cast<const v4f*>(p);
}
}  // namespace

// Phase 1: chunk-local EMA accumulation with s_in = 0.  One thread per
// (chain, chunk k) for k in [0, K-1); chunk K-1's B is never needed.
__global__ __launch_bounds__(256) void spec_ema_phase1(
    const float* __restrict__ x, float* __restrict__ bws) {
  const int g = blockIdx.x * 256 + threadIdx.x;   // [0, CHAINS*(K-1)), exact
  const int chain = g % CHAINS;
  const int k = g / CHAINS;
  const int b = chain / FG, fg = chain % FG;

  const size_t base =
      ((size_t)b * Cdim * Tdim + (size_t)k * L) * Fdim + (size_t)fg * 4;
  const float* p0 = x + base;                       // c = 0
  const float* p1 = p0 + (size_t)Tdim * Fdim;       // c = 1

  v4f s = 0.0f;
#pragma unroll 8
  for (int j = 0; j < L; ++j) {
    v4f x0 = ld4(p0 + (size_t)j * Fdim);
    v4f x1 = ld4(p1 + (size_t)j * Fdim);
    v4f abs2 = x0 * x0 + x1 * x1;
    s = s * kAlpha + abs2 * kOneMinusAlpha;
  }
  // layout: bws[k][chain] as float4  (g == k*CHAINS + chain)
  *reinterpret_cast<v4f*>(bws + (size_t)g * 4) = s;
}

// Phase 2: per-chain serial scan over chunks; in-place rewrite of bws so
// slot [k][chain] holds s_in(k) (the state ENTERING chunk k).
//   s_in(0) = state;  s_in(k+1) = a^L * s_in(k) + B_k.
// 1536 threads total; bws is 6.1 MB (L2/L3-resident); ~250 short serial
// iterations -> a few microseconds.
__global__ __launch_bounds__(256) void spec_ema_phase2(
    const float* __restrict__ state, float* __restrict__ bws) {
  const int chain = blockIdx.x * 256 + threadIdx.x;  // [0, CHAINS), exact
  const int fg = chain % FG;

  v4f s = ld4(state + (size_t)fg * 4);
  for (int k = 0; k < K; ++k) {
    float* slot = bws + ((size_t)k * CHAINS + chain) * 4;
    v4f Bk = 0.0f;
    if (k < K - 1) Bk = ld4(slot);   // slot K-1 was never written by phase1
    *reinterpret_cast<v4f*>(slot) = s;
    s = s * kAlphaL + Bk;
  }
}

// Phase 3: load incoming state (one load), scan chunk, normalize, write.
__global__ __launch_bounds__(256) void spec_ema_phase3(
    const float* __restrict__ x, const float* __restrict__ bws,
    float* __restrict__ out) {
  const int g = blockIdx.x * 256 + threadIdx.x;   // [0, CHAINS*K), exact
  const int chain = g % CHAINS;
  const int k = g / CHAINS;
  const int b = chain / FG, fg = chain % FG;

  v4f s = ld4(bws + (size_t)g * 4);               // s_in(k), from phase2

  const size_t base =
      ((size_t)b * Cdim * Tdim + (size_t)k * L) * Fdim + (size_t)fg * 4;
  const float* p0 = x + base;
  const float* p1 = p0 + (size_t)Tdim * Fdim;
  float* q0 = out + base;
  float* q1 = q0 + (size_t)Tdim * Fdim;

#pragma unroll 4
  for (int j = 0; j < L; ++j) {
    v4f x0 = ld4(p0 + (size_t)j * Fdim);
    v4f x1 = ld4(p1 + (size_t)j * Fdim);
    v4f abs2 = x0 * x0 + x1 * x1;
    s = s * kAlpha + abs2 * kOneMinusAlpha;
    v4f r;
    r.x = rsqrtf(s.x);
    r.y = rsqrtf(s.y);
    r.z = rsqrtf(s.z);
    r.w = rsqrtf(s.w);
    v4f y0 = x0 * r;
    v4f y1 = x1 * r;
    __builtin_nontemporal_store(y0, reinterpret_cast<v4f*>(q0 + (size_t)j * Fdim));
    __builtin_nontemporal_store(y1, reinterpret_cast<v4f*>(q1 + (size_t)j * Fdim));
  }

  if (k == K - 1) {
    // final_state [64, 1, 96] appended after y
    *reinterpret_cast<v4f*>(out + (size_t)Bdim * Cdim * Tdim * Fdim +
                            (size_t)b * Fdim + (size_t)fg * 4) = s;
  }
}

extern "C" void kernel_launch(void* const* d_in, const int* in_sizes, int n_in,
                              void* d_out, int out_size, void* d_ws, size_t ws_size,
                              hipStream_t stream) {
  const float* x = (const float*)d_in[0];      // [64, 2, 4000, 96] f32
  const float* state = (const float*)d_in[1];  // [1, 1, 96] f32
  float* out = (float*)d_out;
  float* bws = (float*)d_ws;                   // needs CHAINS*K*16 B ~= 6.14 MB

  spec_ema_phase1<<<CHAINS * (K - 1) / 256, 256, 0, stream>>>(x, bws);
  spec_ema_phase2<<<CHAINS / 256, 256, 0, stream>>>(state, bws);
  spec_ema_phase3<<<CHAINS * K / 256, 256, 0, stream>>>(x, bws, out);
}

// Round 3
// 368.500 us; speedup vs baseline: 1.0670x; 1.0670x over previous
//
#include <hip/hip_runtime.h>

// SpecEMA: y[b,c,t,f] = x[b,c,t,f] / sqrt(s[b,t,f]),
//   s_t = ALPHA*s_{t-1} + (1-ALPHA)*(x[b,0,t,f]^2 + x[b,1,t,f]^2), s_{-1}=state[f]
// Outputs: y [64,2,4000,96] then final_state [64,1,96], flat-concatenated in d_out.
//
// Two-phase linear-scan decomposition over K chunks of length L (T = K*L):
//   phase1: B_k = chunk-local EMA with s_in = 0   (one thread per chain*chunk)
//   phase3: recombine prefix from bws (O(K) fma loop — loads are independent
//           of s so they pipeline; ~0.3 us/thread, hidden), then scan chunk,
//           normalize, NT-store y.
//
// R2 lesson: a separate phase2 scan kernel is a net LOSS (1536 threads = 6
// blocks, ~10-15 us serial, to save a hidden 0.3 us loop). Removed again.
//
// K=200/L=20 (R1 was 100/40): 1194/1200 blocks (~4.7 blocks/CU, ~19
// waves/CU) — clean 2x-occupancy ablation on the R1 structure to test the
// latency-hiding hypothesis. Phase1 unroll 10 => 20 loads in flight at
// ~100 VGPRs (5 waves/SIMD). Phase3 reads x nontemporally (last consumer;
// still hits L3 where phase1 left it).

namespace {
constexpr int Bdim = 64, Cdim = 2, Tdim = 4000, Fdim = 96;
constexpr int K = 200, L = 20;             // T = K * L
constexpr int FG = Fdim / 4;               // 24 float4 groups per (b, c, t)
constexpr int CHAINS = Bdim * FG;          // 1536 float4-chains
constexpr float kAlpha = 0.99f;
constexpr float kOneMinusAlpha = 0.01f;    // float(1.0 - 0.99)
constexpr float kAlphaL = 0.81790694f;     // 0.99^20

typedef float v4f __attribute__((ext_vector_type(4)));

__device__ __forceinline__ v4f ld4(const float* p) {
  return *reinterpret_cast<const v4f*>(p);
}
__device__ __forceinline__ v4f ld4_nt(const float* p) {
  return __builtin_nontemporal_load(reinterpret_cast<const v4f*>(p));
}
}  // namespace

// Phase 1: chunk-local EMA accumulation with s_in = 0.  One thread per
// (chain, chunk k) for k in [0, K-1); chunk K-1's B is never needed.
__global__ __launch_bounds__(256) void spec_ema_phase1(
    const float* __restrict__ x, float* __restrict__ bws) {
  const int g = blockIdx.x * 256 + threadIdx.x;   // [0, CHAINS*(K-1)), exact
  const int chain = g % CHAINS;
  const int k = g / CHAINS;
  const int b = chain / FG, fg = chain % FG;

  const size_t base =
      ((size_t)b * Cdim * Tdim + (size_t)k * L) * Fdim + (size_t)fg * 4;
  const float* p0 = x + base;                       // c = 0
  const float* p1 = p0 + (size_t)Tdim * Fdim;       // c = 1

  v4f s = 0.0f;
#pragma unroll 10
  for (int j = 0; j < L; ++j) {
    v4f x0 = ld4(p0 + (size_t)j * Fdim);
    v4f x1 = ld4(p1 + (size_t)j * Fdim);
    v4f abs2 = x0 * x0 + x1 * x1;
    s = s * kAlpha + abs2 * kOneMinusAlpha;
  }
  // layout: bws[k][chain] as float4  (g == k*CHAINS + chain)
  *reinterpret_cast<v4f*>(bws + (size_t)g * 4) = s;
}

// Phase 3: recombine chunk prefix, then scan + normalize + write.
__global__ __launch_bounds__(256) void spec_ema_phase3(
    const float* __restrict__ x, const float* __restrict__ state,
    const float* __restrict__ bws, float* __restrict__ out) {
  const int g = blockIdx.x * 256 + threadIdx.x;   // [0, CHAINS*K), exact
  const int chain = g % CHAINS;
  const int k = g / CHAINS;
  const int b = chain / FG, fg = chain % FG;

  // s_in = a^(k*L) * s0 + sum_{m<k} a^((k-1-m)*L) * B_m
  // bws loads are independent of s -> fully pipelined; chain is k fma.
  v4f s = ld4(state + (size_t)fg * 4);
#pragma unroll 4
  for (int m = 0; m < k; ++m) {
    v4f bm = ld4(bws + ((size_t)m * CHAINS + chain) * 4);
    s = s * kAlphaL + bm;
  }

  const size_t base =
      ((size_t)b * Cdim * Tdim + (size_t)k * L) * Fdim + (size_t)fg * 4;
  const float* p0 = x + base;
  const float* p1 = p0 + (size_t)Tdim * Fdim;
  float* q0 = out + base;
  float* q1 = q0 + (size_t)Tdim * Fdim;

#pragma unroll 5
  for (int j = 0; j < L; ++j) {
    v4f x0 = ld4_nt(p0 + (size_t)j * Fdim);
    v4f x1 = ld4_nt(p1 + (size_t)j * Fdim);
    v4f abs2 = x0 * x0 + x1 * x1;
    s = s * kAlpha + abs2 * kOneMinusAlpha;
    v4f r;
    r.x = rsqrtf(s.x);
    r.y = rsqrtf(s.y);
    r.z = rsqrtf(s.z);
    r.w = rsqrtf(s.w);
    v4f y0 = x0 * r;
    v4f y1 = x1 * r;
    __builtin_nontemporal_store(y0, reinterpret_cast<v4f*>(q0 + (size_t)j * Fdim));
    __builtin_nontemporal_store(y1, reinterpret_cast<v4f*>(q1 + (size_t)j * Fdim));
  }

  if (k == K - 1) {
    // final_state [64, 1, 96] appended after y
    *reinterpret_cast<v4f*>(out + (size_t)Bdim * Cdim * Tdim * Fdim +
                            (size_t)b * Fdim + (size_t)fg * 4) = s;
  }
}

extern "C" void kernel_launch(void* const* d_in, const int* in_sizes, int n_in,
                              void* d_out, int out_size, void* d_ws, size_t ws_size,
                              hipStream_t stream) {
  const float* x = (const float*)d_in[0];      // [64, 2, 4000, 96] f32
  const float* state = (const float*)d_in[1];  // [1, 1, 96] f32
  float* out = (float*)d_out;
  float* bws = (float*)d_ws;                   // needs CHAINS*(K-1)*16 B ~= 4.9 MB

  spec_ema_phase1<<<CHAINS * (K - 1) / 256, 256, 0, stream>>>(x, bws);
  spec_ema_phase3<<<CHAINS * K / 256, 256, 0, stream>>>(x, state, bws, out);
}